// Round 9
// baseline (5043.849 us; speedup 1.0000x reference)
//
#include <hip/hip_runtime.h>
#include <stdint.h>

// SGL/LightGCN 3-layer propagation on MI355X (gfx950).
// ego=[200000,64] f32; 4M COO edges; per layer y[row] += val * x[col].
//
// v6 (resubmit): bucket-grouped (NOT row-sorted) edges + LDS-tile SpMM.
//  Build: per-wg histogram over 3125 buckets (LDS) -> flat scan (b-major,
//  g-minor) -> binning where each of 128 writer-wgs streams into its OWN
//  (bucket,wg) segments via LDS cursors. One 64B line is written by one wg
//  (boundaries aside) -> kills the measured 232MB line-amplified writeback
//  of v5's global-atomic binning. Segments pack contiguously per bucket, so
//  each bucket's edges are contiguous; no within-bucket sort needed.
//  SpMM: one wg per bucket; 16KB LDS y-tile (64 rows x 64 dims); per edge:
//  coalesced 256B gather of x[col] + LDS f32 atomicAdd into tile row;
//  4-deep unrolled independent gathers; epilogue = coalesced tile store
//  with fused acc update. Zero f32 global atomics.
//
// ws: A (51.2MB) | B (51.2MB; ghist 1.6MB aliased during build) |
//     bcv (32MB) | bucketBase (12.5KB).  ~134.4MB.

constexpr int N_USER = 100000;
constexpr int NN     = 200000;            // N_NODES
constexpr int NE     = 4000000;           // N_EDGES
constexpr int EMB    = 64;
constexpr int RPB    = 64;                // rows per bucket
constexpr int NB     = NN / RPB;          // 3125 buckets (exact)
constexpr int COLB   = 18;                // col bits (200000 < 2^18)
constexpr int CMASK  = (1 << COLB) - 1;
constexpr int NWG    = 128;               // binning writer groups
constexpr int EPW    = NE / NWG;          // 31250 edges per writer group
constexpr int SCN    = NB * NWG;          // 400000 scan elements

// ---------------------------------------------------------------- init:
// A = concat(user,item); acc(d_out) = same
__global__ __launch_bounds__(256) void init_kernel(
    const float4* __restrict__ user, const float4* __restrict__ item,
    float4* __restrict__ A, float4* __restrict__ acc)
{
    const int64_t half  = (int64_t)N_USER * EMB / 4;
    const int64_t total = (int64_t)NN * EMB / 4;
    for (int64_t i = blockIdx.x * (int64_t)blockDim.x + threadIdx.x; i < total;
         i += (int64_t)gridDim.x * blockDim.x) {
        const float4 v = (i < half) ? user[i] : item[i - half];
        A[i] = v;
        acc[i] = v;
    }
}

// ---------------------------------------------------------------- phase A:
// per-writer-group bucket histogram (LDS), flushed to ghist[b*NWG + g]
__global__ __launch_bounds__(1024) void ghist_kernel(
    const int* __restrict__ rows, int* __restrict__ ghist)
{
    __shared__ int lh[NB];
    const int g = blockIdx.x, t = threadIdx.x;
    for (int i = t; i < NB; i += 1024) lh[i] = 0;
    __syncthreads();
    const int lo = g * EPW, hi = lo + EPW;
    for (int e = lo + t; e < hi; e += 1024)
        atomicAdd(&lh[rows[e] >> 6], 1);               // RPB = 64
    __syncthreads();
    for (int i = t; i < NB; i += 1024)
        ghist[(int64_t)i * NWG + g] = lh[i];
}

// ---------------------------------------------------------------- phase B:
// in-place exclusive scan of ghist[SCN] (b-major, g-minor); emits
// bucketBase[b] at every (b,0) position; single 1024-thread workgroup.
__global__ __launch_bounds__(1024) void scan_kernel(
    int* __restrict__ gh, int* __restrict__ bucketBase)
{
    __shared__ int sums[1024];
    const int t = threadIdx.x;
    constexpr int CH = (SCN + 1023) / 1024;            // 391
    const int start = t * CH;
    const int end   = (start + CH < SCN) ? start + CH : SCN;

    int s = 0;
    for (int i = start; i < end; ++i) s += gh[i];
    sums[t] = s;
    __syncthreads();
    for (int off = 1; off < 1024; off <<= 1) {
        const int x = sums[t];
        const int y = (t >= off) ? sums[t - off] : 0;
        __syncthreads();
        sums[t] = x + y;
        __syncthreads();
    }
    int run = (t == 0) ? 0 : sums[t - 1];
    for (int i = start; i < end; ++i) {
        const int v = gh[i];
        gh[i] = run;                                   // exclusive base
        if ((i & (NWG - 1)) == 0) bucketBase[i / NWG] = run;
        run += v;
    }
    if (t == 0) bucketBase[NB] = NE;
}

// ---------------------------------------------------------------- phase C:
// binning: wg g claims slots in its private (b,g) segments via LDS cursors;
// all writes to a given line come from one wg -> lines fill in its L2.
__global__ __launch_bounds__(1024) void bin_kernel(
    const int* __restrict__ rows, const int* __restrict__ cols,
    const int* __restrict__ vals_bits, const int* __restrict__ base,
    int2* __restrict__ bcv)
{
    __shared__ int lcur[NB];
    const int g = blockIdx.x, t = threadIdx.x;
    for (int i = t; i < NB; i += 1024)
        lcur[i] = base[(int64_t)i * NWG + g];
    __syncthreads();
    const int lo = g * EPW, hi = lo + EPW;
    for (int e = lo + t; e < hi; e += 1024) {
        const int r = rows[e];
        const int p = atomicAdd(&lcur[r >> 6], 1);
        bcv[p] = make_int2(((r & 63) << COLB) | cols[e], vals_bits[e]);
    }
}

// ---------------------------------------------------------------- spmm:
// one wg (4 waves) per bucket; LDS y-tile [64][64] f32; per edge one
// coalesced 256B gather + LDS atomic row add; 4-deep unrolled gathers.
template<bool FINAL>
__global__ __launch_bounds__(256) void spmm_bucket_kernel(
    const int* __restrict__ bucketBase, const int2* __restrict__ bcv,
    const float* __restrict__ x, float4* __restrict__ y4,
    float4* __restrict__ acc4)
{
    __shared__ float tile[RPB * EMB];                  // 16 KB
    float4* t4 = (float4*)tile;
    const int b = blockIdx.x, t = threadIdx.x;
    for (int i = t; i < RPB * EMB / 4; i += 256)
        t4[i] = make_float4(0.f, 0.f, 0.f, 0.f);
    __syncthreads();

    const int lane = t & 63, wv = t >> 6;              // 4 waves
    const int e0 = bucketBase[b], e1 = bucketBase[b + 1];
    int e = e0 + wv;
    for (; e + 12 < e1; e += 16) {                     // 4 edges/wave in flight
        const int2 c0 = bcv[e];
        const int2 c1 = bcv[e + 4];
        const int2 c2 = bcv[e + 8];
        const int2 c3 = bcv[e + 12];
        const float x0 = x[(int64_t)(c0.x & CMASK) * EMB + lane];
        const float x1 = x[(int64_t)(c1.x & CMASK) * EMB + lane];
        const float x2 = x[(int64_t)(c2.x & CMASK) * EMB + lane];
        const float x3 = x[(int64_t)(c3.x & CMASK) * EMB + lane];
        atomicAdd(&tile[(((unsigned)c0.x) >> COLB) * EMB + lane],
                  __builtin_bit_cast(float, c0.y) * x0);
        atomicAdd(&tile[(((unsigned)c1.x) >> COLB) * EMB + lane],
                  __builtin_bit_cast(float, c1.y) * x1);
        atomicAdd(&tile[(((unsigned)c2.x) >> COLB) * EMB + lane],
                  __builtin_bit_cast(float, c2.y) * x2);
        atomicAdd(&tile[(((unsigned)c3.x) >> COLB) * EMB + lane],
                  __builtin_bit_cast(float, c3.y) * x3);
    }
    for (; e < e1; e += 4) {                           // tail
        const int2 c = bcv[e];
        const float xv = x[(int64_t)(c.x & CMASK) * EMB + lane];
        atomicAdd(&tile[(((unsigned)c.x) >> COLB) * EMB + lane],
                  __builtin_bit_cast(float, c.y) * xv);
    }
    __syncthreads();

    for (int i = t; i < RPB * EMB / 4; i += 256) {     // coalesced epilogue
        const float4 s = t4[i];
        const int64_t idx = (int64_t)b * (RPB * EMB / 4) + i;
        float4 a = acc4[idx];
        if constexpr (FINAL) {
            a.x = (a.x + s.x) * 0.25f; a.y = (a.y + s.y) * 0.25f;
            a.z = (a.z + s.z) * 0.25f; a.w = (a.w + s.w) * 0.25f;
            acc4[idx] = a;
        } else {
            y4[idx] = s;
            a.x += s.x; a.y += s.y; a.z += s.z; a.w += s.w;
            acc4[idx] = a;
        }
    }
}

extern "C" void kernel_launch(void* const* d_in, const int* in_sizes, int n_in,
                              void* d_out, int out_size, void* d_ws, size_t ws_size,
                              hipStream_t stream)
{
    const float* user = (const float*)d_in[0];
    const float* item = (const float*)d_in[1];
    const int*   rows = (const int*)d_in[2];
    const int*   cols = (const int*)d_in[3];
    const int*   vals = (const int*)d_in[4];   // f32 bits

    float* acc = (float*)d_out;                // [NN, EMB]

    // ---- workspace carve-up (~134.4MB) ----
    char* ws = (char*)d_ws;
    const size_t VEC_B = (size_t)NN * EMB * sizeof(float);   // 51.2 MB
    float* A     = (float*)(ws);
    float* B     = (float*)(ws + VEC_B);
    int*   ghist = (int*)  (ws + VEC_B);       // 1.6MB, aliases B during build
    int2*  bcv   = (int2*) (ws + 2 * VEC_B);   // 32 MB, lives through all layers
    int*   bucketBase = (int*)(ws + 2 * VEC_B + (size_t)NE * sizeof(int2));

    const dim3 blk256(256), blk1k(1024);
    const int eltBlocks = 1024;

    // ---- build phase ----
    init_kernel<<<eltBlocks, blk256, 0, stream>>>(
        (const float4*)user, (const float4*)item, (float4*)A, (float4*)acc);
    ghist_kernel<<<NWG, blk1k, 0, stream>>>(rows, ghist);
    scan_kernel<<<1, blk1k, 0, stream>>>(ghist, bucketBase);
    bin_kernel<<<NWG, blk1k, 0, stream>>>(rows, cols, vals, ghist, bcv);

    // ---- 3 propagation layers (acc fused) ----
    spmm_bucket_kernel<false><<<NB, blk256, 0, stream>>>(bucketBase, bcv,
        A, (float4*)B, (float4*)acc);
    spmm_bucket_kernel<false><<<NB, blk256, 0, stream>>>(bucketBase, bcv,
        B, (float4*)A, (float4*)acc);
    spmm_bucket_kernel<true><<<NB, blk256, 0, stream>>>(bucketBase, bcv,
        A, (float4*)nullptr, (float4*)acc);
}